// Round 1
// baseline (697.066 us; speedup 1.0000x reference)
//
#include <hip/hip_runtime.h>
#include <stdint.h>

#define MQ 256
#define NB 50000
#define KD 2048
#define BN 64
#define BK 64

typedef __attribute__((ext_vector_type(8))) short bf16x8;
typedef __attribute__((ext_vector_type(4))) float f32x4;

__device__ __forceinline__ unsigned int pack_bf16(float a, float b) {
  unsigned int ua = __float_as_uint(a);
  ua += 0x7fffu + ((ua >> 16) & 1u);
  unsigned int ub = __float_as_uint(b);
  ub += 0x7fffu + ((ub >> 16) & 1u);
  return (ua >> 16) | (ub & 0xffff0000u);
}

__device__ __forceinline__ float wave_sum(float v) {
#pragma unroll
  for (int o = 32; o > 0; o >>= 1) v += __shfl_down(v, o, 64);
  return v;
}
__device__ __forceinline__ float wave_max(float v) {
#pragma unroll
  for (int o = 32; o > 0; o >>= 1) v = fmaxf(v, __shfl_down(v, o, 64));
  return v;
}

// ---------------- kernel 1: queries fp32 -> bf16 (+ q norms) ----------------
__global__ __launch_bounds__(256) void prep_q(const float* __restrict__ q,
                                              unsigned short* __restrict__ qbf,
                                              float* __restrict__ qn) {
  const int b = blockIdx.x, tid = threadIdx.x;
  const float* row = q + (size_t)b * KD;
  float4 v0 = *(const float4*)(row + tid * 8);
  float4 v1 = *(const float4*)(row + tid * 8 + 4);
  float sq = v0.x * v0.x + v0.y * v0.y + v0.z * v0.z + v0.w * v0.w +
             v1.x * v1.x + v1.y * v1.y + v1.z * v1.z + v1.w * v1.w;
  uint4 o;
  o.x = pack_bf16(v0.x, v0.y);
  o.y = pack_bf16(v0.z, v0.w);
  o.z = pack_bf16(v1.x, v1.y);
  o.w = pack_bf16(v1.z, v1.w);
  *(uint4*)(qbf + (size_t)b * KD + tid * 8) = o;
  sq = wave_sum(sq);
  __shared__ float s4[4];
  if ((tid & 63) == 0) s4[tid >> 6] = sq;
  __syncthreads();
  if (tid == 0) qn[b] = sqrtf(s4[0] + s4[1] + s4[2] + s4[3]);
}

// ---------------- kernel 2: bf16 MFMA GEMM, fused b-norm, writes scores ----
// Block tile: 256(M) x 64(N), BK=64, 4 waves, each wave 64x64 via 4x4 MFMA
// 16x16x32 tiles. A (queries, bf16 in ws) staged via global_load_lds width-16.
// B (bank, fp32 in HBM) loaded fp32, sum-of-squares accumulated (b_norm fused),
// converted to bf16 in-register, ds_write to LDS.
__global__ __launch_bounds__(256, 3) void gemm_scores(
    const float* __restrict__ bank, const unsigned short* __restrict__ qbf,
    const float* __restrict__ qn, float* __restrict__ out_scores) {
  __shared__ alignas(16) unsigned short As[MQ * BK];  // 32 KB [m][k]
  __shared__ alignas(16) unsigned short Bs[BN * BK];  // 8 KB  [n][k]
  __shared__ float qn_s[MQ];
  __shared__ float bsq_s[256];
  __shared__ float bn_s[BN];

  const int tid = threadIdx.x;
  const int w = tid >> 6;
  const int lane = tid & 63;
  const int n0 = blockIdx.x * BN;

  qn_s[tid] = qn[tid];

  f32x4 acc[4][4] = {};

  // B staging: thread t -> row t>>2 (block-local), k-segment (t&3)*16
  const int br = tid >> 2;
  const int bseg = (tid & 3) * 16;
  int brow = n0 + br;
  if (brow >= NB) brow = NB - 1;  // clamp; masked at store
  const float* bsrc = bank + (size_t)brow * KD + bseg;

  const int a_row_in_grp = lane >> 3;
  const int a_colb = (lane & 7) * 8;
  float bsq = 0.f;

  for (int kt = 0; kt < KD / BK; ++kt) {
    const int k0 = kt * BK;
    // ---- A stage: 32 KB bf16, 8 async 1KB wave-loads per wave ----
#pragma unroll
    for (int i = 0; i < 8; ++i) {
      const int row = w * 64 + i * 8 + a_row_in_grp;
      const unsigned short* src = qbf + (size_t)row * KD + k0 + a_colb;
      unsigned short* dst = &As[row * BK + a_colb];
      __builtin_amdgcn_global_load_lds(
          (const __attribute__((address_space(1))) unsigned int*)src,
          (__attribute__((address_space(3))) unsigned int*)dst, 16, 0, 0);
    }
    // ---- B stage: 16 fp32 per thread, fused sq-sum, cvt bf16 ----
    float4 f0 = *(const float4*)(bsrc + k0);
    float4 f1 = *(const float4*)(bsrc + k0 + 4);
    float4 f2 = *(const float4*)(bsrc + k0 + 8);
    float4 f3 = *(const float4*)(bsrc + k0 + 12);
    bsq += f0.x * f0.x + f0.y * f0.y + f0.z * f0.z + f0.w * f0.w +
           f1.x * f1.x + f1.y * f1.y + f1.z * f1.z + f1.w * f1.w +
           f2.x * f2.x + f2.y * f2.y + f2.z * f2.z + f2.w * f2.w +
           f3.x * f3.x + f3.y * f3.y + f3.z * f3.z + f3.w * f3.w;
    uint4 w0, w1;
    w0.x = pack_bf16(f0.x, f0.y);
    w0.y = pack_bf16(f0.z, f0.w);
    w0.z = pack_bf16(f1.x, f1.y);
    w0.w = pack_bf16(f1.z, f1.w);
    w1.x = pack_bf16(f2.x, f2.y);
    w1.y = pack_bf16(f2.z, f2.w);
    w1.z = pack_bf16(f3.x, f3.y);
    w1.w = pack_bf16(f3.z, f3.w);
    *(uint4*)&Bs[br * BK + bseg] = w0;
    *(uint4*)&Bs[br * BK + bseg + 8] = w1;
    __syncthreads();
    // ---- compute: 2 k-steps x (8 ds_read_b128 + 16 MFMA) per wave ----
#pragma unroll
    for (int s = 0; s < 2; ++s) {
      bf16x8 af[4], bfv[4];
#pragma unroll
      for (int t = 0; t < 4; ++t) {
        af[t] = *(const bf16x8*)&As[(w * 64 + t * 16 + (lane & 15)) * BK +
                                    s * 32 + (lane >> 4) * 8];
        bfv[t] = *(const bf16x8*)&Bs[(t * 16 + (lane & 15)) * BK + s * 32 +
                                     (lane >> 4) * 8];
      }
#pragma unroll
      for (int tm = 0; tm < 4; ++tm)
#pragma unroll
        for (int tn = 0; tn < 4; ++tn)
          acc[tm][tn] = __builtin_amdgcn_mfma_f32_16x16x32_bf16(
              af[tm], bfv[tn], acc[tm][tn], 0, 0, 0);
    }
    __syncthreads();
  }

  // ---- b-norm reduce: 4 partials per row ----
  bsq_s[tid] = bsq;
  __syncthreads();
  if (tid < BN)
    bn_s[tid] = sqrtf(bsq_s[tid * 4] + bsq_s[tid * 4 + 1] + bsq_s[tid * 4 + 2] +
                      bsq_s[tid * 4 + 3]);
  __syncthreads();

  // ---- epilogue: scale by 1/max(qn*bn, eps), store ----
  const int quad = lane >> 4, nl = lane & 15;
#pragma unroll
  for (int tn = 0; tn < 4; ++tn) {
    const int gn = n0 + tn * 16 + nl;
    if (gn >= NB) continue;
    const float bn = bn_s[tn * 16 + nl];
#pragma unroll
    for (int tm = 0; tm < 4; ++tm) {
#pragma unroll
      for (int r = 0; r < 4; ++r) {
        const int m = w * 64 + tm * 16 + quad * 4 + r;
        const float sc = acc[tm][tn][r] / fmaxf(qn_s[m] * bn, 1e-12f);
        out_scores[(size_t)m * NB + gn] = sc;
      }
    }
  }
}

// ---------------- kernel 3: per-query argmax with fp32 rescue ----------------
// bf16 score noise sigma ~3.4e-5; collect all candidates within 2e-3 (~30
// sigma) of the approx max and rescore with exact fp32 dots; argmax of dot/bn
// is monotonic-equivalent to the reference score (qn constant per row).
__global__ __launch_bounds__(256) void argmax_rescue(
    const float* __restrict__ scores, const float* __restrict__ q,
    const float* __restrict__ bank, float* __restrict__ out_idx) {
  const int b = blockIdx.x, tid = threadIdx.x;
  const int w = tid >> 6, lane = tid & 63;
  const float* row = scores + (size_t)b * NB;

  float vmax = -1e30f;
  for (int i = tid; i < NB; i += 256) vmax = fmaxf(vmax, row[i]);
  vmax = wave_max(vmax);
  __shared__ float red[4];
  if (lane == 0) red[w] = vmax;
  __syncthreads();
  const float bmax = fmaxf(fmaxf(red[0], red[1]), fmaxf(red[2], red[3]));
  const float thr = bmax - 2e-3f;

  __shared__ int cand[64];
  __shared__ int cnt;
  if (tid == 0) cnt = 0;
  __syncthreads();
  for (int i = tid; i < NB; i += 256) {
    if (row[i] >= thr) {
      int c = atomicAdd(&cnt, 1);
      if (c < 64) cand[c] = i;
    }
  }
  __syncthreads();
  const int nc = min(cnt, 64);

  __shared__ float dd[4], ss[4];
  float best = -1e30f;
  int bidx = 0x7fffffff;
  const float* qrow = q + (size_t)b * KD;
  for (int c = 0; c < nc; ++c) {
    const int idx = cand[c];
    const float* brow = bank + (size_t)idx * KD;
    float d = 0.f, s = 0.f;
#pragma unroll
    for (int j = 0; j < 8; ++j) {
      const float bv = brow[tid * 8 + j];
      const float qv = qrow[tid * 8 + j];
      d = fmaf(qv, bv, d);
      s = fmaf(bv, bv, s);
    }
    d = wave_sum(d);
    s = wave_sum(s);
    if (lane == 0) {
      dd[w] = d;
      ss[w] = s;
    }
    __syncthreads();
    const float dt = dd[0] + dd[1] + dd[2] + dd[3];
    const float st = ss[0] + ss[1] + ss[2] + ss[3];
    const float sc = dt / fmaxf(sqrtf(st), 1e-12f);
    if (sc > best || (sc == best && idx < bidx)) {
      best = sc;
      bidx = idx;
    }
    __syncthreads();
  }
  if (tid == 0) out_idx[b] = (float)bidx;
}

extern "C" void kernel_launch(void* const* d_in, const int* in_sizes, int n_in,
                              void* d_out, int out_size, void* d_ws,
                              size_t ws_size, hipStream_t stream) {
  const float* queries = (const float*)d_in[0];  // [256, 2048] fp32
  const float* bank = (const float*)d_in[1];     // [50000, 2048] fp32
  float* out = (float*)d_out;                    // [256 idx | 256*50000 scores]
  float* out_scores = out + MQ;

  unsigned short* qbf = (unsigned short*)d_ws;             // 1 MB bf16 queries
  float* qn = (float*)((char*)d_ws + (size_t)MQ * KD * 2); // 256 q-norms

  prep_q<<<MQ, 256, 0, stream>>>(queries, qbf, qn);
  gemm_scores<<<(NB + BN - 1) / BN, 256, 0, stream>>>(bank, qbf, qn,
                                                      out_scores);
  argmax_rescue<<<MQ, 256, 0, stream>>>(out_scores, queries, bank, out);
}

// Round 2
// 641.708 us; speedup vs baseline: 1.0863x; 1.0863x over previous
//
#include <hip/hip_runtime.h>
#include <stdint.h>

#define MQ 256
#define NB 50000
#define KD 2048
#define BN 64
#define BK 64
#define KT (KD / BK)
#define NBLK ((NB + BN - 1) / BN)  // 782

typedef __attribute__((ext_vector_type(8))) short bf16x8;
typedef __attribute__((ext_vector_type(4))) float f32x4;

__device__ __forceinline__ unsigned int pack_bf16(float a, float b) {
  unsigned int ua = __float_as_uint(a);
  ua += 0x7fffu + ((ua >> 16) & 1u);
  unsigned int ub = __float_as_uint(b);
  ub += 0x7fffu + ((ub >> 16) & 1u);
  return (ua >> 16) | (ub & 0xffff0000u);
}

// order-preserving float<->uint map (total order, works for negatives)
__device__ __forceinline__ unsigned int ordf(float f) {
  unsigned int u = __float_as_uint(f);
  return (u & 0x80000000u) ? ~u : (u | 0x80000000u);
}
__device__ __forceinline__ float deordf(unsigned int e) {
  unsigned int u = (e & 0x80000000u) ? (e ^ 0x80000000u) : ~e;
  return __uint_as_float(u);
}

__device__ __forceinline__ float wave_sum(float v) {
#pragma unroll
  for (int o = 32; o > 0; o >>= 1) v += __shfl_down(v, o, 64);
  return v;
}

// ---------------- kernel 1: queries fp32 -> bf16 (+ q norms) ----------------
__global__ __launch_bounds__(256) void prep_q(const float* __restrict__ q,
                                              unsigned short* __restrict__ qbf,
                                              float* __restrict__ qn) {
  const int b = blockIdx.x, tid = threadIdx.x;
  const float* row = q + (size_t)b * KD;
  float4 v0 = *(const float4*)(row + tid * 8);
  float4 v1 = *(const float4*)(row + tid * 8 + 4);
  float sq = v0.x * v0.x + v0.y * v0.y + v0.z * v0.z + v0.w * v0.w +
             v1.x * v1.x + v1.y * v1.y + v1.z * v1.z + v1.w * v1.w;
  uint4 o;
  o.x = pack_bf16(v0.x, v0.y);
  o.y = pack_bf16(v0.z, v0.w);
  o.z = pack_bf16(v1.x, v1.y);
  o.w = pack_bf16(v1.z, v1.w);
  *(uint4*)(qbf + (size_t)b * KD + tid * 8) = o;
  sq = wave_sum(sq);
  __shared__ float s4[4];
  if ((tid & 63) == 0) s4[tid >> 6] = sq;
  __syncthreads();
  if (tid == 0) qn[b] = sqrtf(s4[0] + s4[1] + s4[2] + s4[3]);
}

// ---------------- kernel 2: pipelined bf16 MFMA GEMM ----------------
// 256(M) x 64(N) block tile, BK=64. B-stream (fp32 HBM) is software-pipelined
// into registers: tile kt+1's loads issue right after barrier1 and fly during
// the MFMA phase, so barrier2's vmcnt(0) drain finds them already complete.
// Epilogue additionally emits per-(block,m) packed (ordered_score,idx) maxima
// so the argmax pass never rescans the 51 MB score matrix.
__global__ __launch_bounds__(256, 3) void gemm_scores(
    const float* __restrict__ bank, const unsigned short* __restrict__ qbf,
    const float* __restrict__ qn, float* __restrict__ out_scores,
    unsigned long long* __restrict__ bm) {
  __shared__ alignas(16) unsigned short As[MQ * BK];  // 32 KB [m][k]
  __shared__ alignas(16) unsigned short Bs[BN * BK];  // 8 KB  [n][k]
  __shared__ float qn_s[MQ];
  __shared__ float bsq_s[256];
  __shared__ float bn_s[BN];

  const int tid = threadIdx.x;
  const int w = tid >> 6;
  const int lane = tid & 63;
  const int n0 = blockIdx.x * BN;

  qn_s[tid] = qn[tid];

  f32x4 acc[4][4] = {};

  // B staging map: thread t -> block-local row t>>2, 64B k-chunk (t&3)*16
  const int br = tid >> 2;
  const int bseg = (tid & 3) * 16;
  int brow = n0 + br;
  if (brow >= NB) brow = NB - 1;  // clamp; excluded at store
  const float* bsrc = bank + (size_t)brow * KD + bseg;

  const int a_row_in_grp = lane >> 3;
  const int a_colb = (lane & 7) * 8;
  float bsq = 0.f;

  // prologue: preload B tile 0 into registers
  float4 f0 = *(const float4*)(bsrc);
  float4 f1 = *(const float4*)(bsrc + 4);
  float4 f2 = *(const float4*)(bsrc + 8);
  float4 f3 = *(const float4*)(bsrc + 12);

  for (int kt = 0; kt < KT; ++kt) {
    const int k0 = kt * BK;
    // ---- A stage (async global->LDS, L2-resident qbf) ----
#pragma unroll
    for (int i = 0; i < 8; ++i) {
      const int row = w * 64 + i * 8 + a_row_in_grp;
      const unsigned short* src = qbf + (size_t)row * KD + k0 + a_colb;
      unsigned short* dst = &As[row * BK + a_colb];
      __builtin_amdgcn_global_load_lds(
          (const __attribute__((address_space(1))) unsigned int*)src,
          (__attribute__((address_space(3))) unsigned int*)dst, 16, 0, 0);
    }
    // ---- consume current B regs: fused sq-sum + cvt bf16 + ds_write ----
    bsq += f0.x * f0.x + f0.y * f0.y + f0.z * f0.z + f0.w * f0.w +
           f1.x * f1.x + f1.y * f1.y + f1.z * f1.z + f1.w * f1.w +
           f2.x * f2.x + f2.y * f2.y + f2.z * f2.z + f2.w * f2.w +
           f3.x * f3.x + f3.y * f3.y + f3.z * f3.z + f3.w * f3.w;
    uint4 p0, p1;
    p0.x = pack_bf16(f0.x, f0.y);
    p0.y = pack_bf16(f0.z, f0.w);
    p0.z = pack_bf16(f1.x, f1.y);
    p0.w = pack_bf16(f1.z, f1.w);
    p1.x = pack_bf16(f2.x, f2.y);
    p1.y = pack_bf16(f2.z, f2.w);
    p1.z = pack_bf16(f3.x, f3.y);
    p1.w = pack_bf16(f3.z, f3.w);
    *(uint4*)&Bs[br * BK + bseg] = p0;
    *(uint4*)&Bs[br * BK + bseg + 8] = p1;
    __syncthreads();  // As + Bs ready
    // ---- prefetch next B tile: in flight during the MFMA phase ----
    if (kt + 1 < KT) {
      const float* p = bsrc + (kt + 1) * BK;
      f0 = *(const float4*)(p);
      f1 = *(const float4*)(p + 4);
      f2 = *(const float4*)(p + 8);
      f3 = *(const float4*)(p + 12);
    }
    // ---- compute: 2 k-steps x (8 ds_read_b128 + 16 MFMA) per wave ----
#pragma unroll
    for (int s = 0; s < 2; ++s) {
      bf16x8 af[4], bfv[4];
#pragma unroll
      for (int t = 0; t < 4; ++t) {
        af[t] = *(const bf16x8*)&As[(w * 64 + t * 16 + (lane & 15)) * BK +
                                    s * 32 + (lane >> 4) * 8];
        bfv[t] = *(const bf16x8*)&Bs[(t * 16 + (lane & 15)) * BK + s * 32 +
                                     (lane >> 4) * 8];
      }
#pragma unroll
      for (int tm = 0; tm < 4; ++tm)
#pragma unroll
        for (int tn = 0; tn < 4; ++tn)
          acc[tm][tn] = __builtin_amdgcn_mfma_f32_16x16x32_bf16(
              af[tm], bfv[tn], acc[tm][tn], 0, 0, 0);
    }
    __syncthreads();  // drains B prefetch too (latency hidden by MFMA)
  }

  // ---- b-norm reduce: 4 partials per row ----
  bsq_s[tid] = bsq;
  __syncthreads();
  if (tid < BN)
    bn_s[tid] = sqrtf(bsq_s[tid * 4] + bsq_s[tid * 4 + 1] + bsq_s[tid * 4 + 2] +
                      bsq_s[tid * 4 + 3]);
  __syncthreads();

  // ---- epilogue: scale, store, and per-(block,m) packed argmax ----
  const int quad = lane >> 4, nl = lane & 15;
#pragma unroll
  for (int tm = 0; tm < 4; ++tm) {
#pragma unroll
    for (int r = 0; r < 4; ++r) {
      const int m = w * 64 + tm * 16 + quad * 4 + r;
      const float qm = qn_s[m];
      unsigned long long best = 0ull;
#pragma unroll
      for (int tn = 0; tn < 4; ++tn) {
        const int gn = n0 + tn * 16 + nl;
        if (gn < NB) {
          const float sc =
              acc[tm][tn][r] / fmaxf(qm * bn_s[tn * 16 + nl], 1e-12f);
          out_scores[(size_t)m * NB + gn] = sc;
          const unsigned long long pk =
              ((unsigned long long)ordf(sc) << 32) | (unsigned int)gn;
          best = pk > best ? pk : best;
        }
      }
#pragma unroll
      for (int mask = 1; mask < 16; mask <<= 1) {
        const unsigned long long o = __shfl_xor(best, mask, 64);
        best = o > best ? o : best;
      }
      if (nl == 0) bm[(size_t)m * NBLK + blockIdx.x] = best;
    }
  }
}

// ---------------- kernel 3: argmax from block maxima + fp32 rescue ---------
// Global approx max from the 782 packed block maxima; blocks within
// delta=2e-3 (~50 sigma of bf16 dot noise) of the max get their 64-score
// segment rescanned; candidates get exact fp32 rescoring (argmax of dot/bn
// is monotonic-equal to the reference score since qn is constant per row).
__global__ __launch_bounds__(256) void argmax_rescue(
    const unsigned long long* __restrict__ bm, const float* __restrict__ scores,
    const float* __restrict__ q, const float* __restrict__ bank,
    float* __restrict__ out_idx) {
  const int b = blockIdx.x, tid = threadIdx.x;
  const int w = tid >> 6, lane = tid & 63;
  const unsigned long long* rbm = bm + (size_t)b * NBLK;

  unsigned long long pmax = 0ull;
  for (int i = tid; i < NBLK; i += 256) {
    const unsigned long long v = rbm[i];
    pmax = v > pmax ? v : pmax;
  }
#pragma unroll
  for (int o = 32; o > 0; o >>= 1) {
    const unsigned long long v = __shfl_down(pmax, o, 64);
    pmax = v > pmax ? v : pmax;
  }
  __shared__ unsigned long long red[4];
  if (lane == 0) red[w] = pmax;
  __syncthreads();
  unsigned long long gmax = red[0];
#pragma unroll
  for (int i = 1; i < 4; ++i) gmax = red[i] > gmax ? red[i] : gmax;
  const float thr = deordf((unsigned int)(gmax >> 32)) - 2e-3f;

  __shared__ int cand[64];
  __shared__ int cnt;
  if (tid == 0) cnt = 0;
  __syncthreads();
  const float* srow = scores + (size_t)b * NB;
  for (int i = tid; i < NBLK; i += 256) {
    const float bmf = deordf((unsigned int)(rbm[i] >> 32));
    if (bmf >= thr) {  // rare (1-3 blocks): rescan its 64 scores
      const int base = i * BN;
      const int lim = min(BN, NB - base);
      for (int j = 0; j < lim; ++j) {
        if (srow[base + j] >= thr) {
          const int c = atomicAdd(&cnt, 1);
          if (c < 64) cand[c] = base + j;
        }
      }
    }
  }
  __syncthreads();
  const int nc = min(cnt, 64);

  __shared__ float dd[4], ss[4];
  float best = -1e30f;
  int bidx = 0x7fffffff;
  const float* qrow = q + (size_t)b * KD;
  for (int c = 0; c < nc; ++c) {
    const int idx = cand[c];
    const float* brow = bank + (size_t)idx * KD;
    float d = 0.f, s = 0.f;
#pragma unroll
    for (int j = 0; j < 8; ++j) {
      const float bv = brow[tid * 8 + j];
      const float qv = qrow[tid * 8 + j];
      d = fmaf(qv, bv, d);
      s = fmaf(bv, bv, s);
    }
    d = wave_sum(d);
    s = wave_sum(s);
    if (lane == 0) {
      dd[w] = d;
      ss[w] = s;
    }
    __syncthreads();
    const float dt = dd[0] + dd[1] + dd[2] + dd[3];
    const float st = ss[0] + ss[1] + ss[2] + ss[3];
    const float sc = dt / fmaxf(sqrtf(st), 1e-12f);
    if (sc > best || (sc == best && idx < bidx)) {
      best = sc;
      bidx = idx;
    }
    __syncthreads();
  }
  if (tid == 0) out_idx[b] = (float)bidx;
}

extern "C" void kernel_launch(void* const* d_in, const int* in_sizes, int n_in,
                              void* d_out, int out_size, void* d_ws,
                              size_t ws_size, hipStream_t stream) {
  const float* queries = (const float*)d_in[0];  // [256, 2048] fp32
  const float* bank = (const float*)d_in[1];     // [50000, 2048] fp32
  float* out = (float*)d_out;                    // [256 idx | 256*50000 scores]
  float* out_scores = out + MQ;

  char* ws = (char*)d_ws;
  unsigned short* qbf = (unsigned short*)ws;                 // 1 MB bf16 queries
  float* qn = (float*)(ws + (size_t)MQ * KD * 2);            // 1 KB q-norms
  unsigned long long* bm =
      (unsigned long long*)(ws + (size_t)MQ * KD * 2 + 2048);  // 1.6 MB maxima

  prep_q<<<MQ, 256, 0, stream>>>(queries, qbf, qn);
  gemm_scores<<<NBLK, 256, 0, stream>>>(bank, qbf, qn, out_scores, bm);
  argmax_rescue<<<MQ, 256, 0, stream>>>(bm, out_scores, queries, bank, out);
}